// Round 1
// baseline (1237.561 us; speedup 1.0000x reference)
//
#include <hip/hip_runtime.h>
#include <math.h>

#define NB 16
#define NS 48
#define NL 64
#define NQ 32
#define NE 300
#define NF 256
#define EPITCH 320
#define SCOFF (66 * EPITCH)                 // float offset of s_conv region
#define DYN_LDS ((SCOFF + 64 * NF) * 4)     // 150016 bytes

__device__ __forceinline__ float wave_reduce_sum(float v) {
#pragma unroll
    for (int off = 32; off; off >>= 1) v += __shfl_xor(v, off, 64);
    return v;
}
__device__ __forceinline__ float wave_reduce_max(float v) {
#pragma unroll
    for (int off = 32; off; off >>= 1) v = fmaxf(v, __shfl_xor(v, off, 64));
    return v;
}
// top-5 over the 64 lanes (one value per lane): returns max and mean of top-5.
__device__ __forceinline__ void top5_pool(float v, int lane, float& mx, float& mn) {
    float sum = 0.f, first = 0.f;
#pragma unroll
    for (int i = 0; i < 5; ++i) {
        float m = wave_reduce_max(v);
        if (i == 0) first = m;
        sum += m;
        unsigned long long msk = __ballot(v == m);
        int leader = __ffsll(msk) - 1;
        if (lane == leader) v = -3.4e38f;   // remove one instance
    }
    mx = first;
    mn = sum * 0.2f;
}

// ---------- kernel 1: pack conv_w [NF][3][300] -> Wtp pairs:
// Wtp[((e2*3 + j)*256 + f)*2 + p] = conv_w[f][j][2*e2+p]
__global__ void wtrans_kernel(const float* __restrict__ conv_w, float* __restrict__ Wtp) {
    int i = blockIdx.x * 256 + threadIdx.x;   // 230400 total
    if (i >= NF * 3 * NE) return;
    int p = i & 1;
    int f = (i >> 1) & 255;
    int rest = i >> 9;          // e2*3 + j
    int j = rest % 3;
    int e2 = rest / 3;
    Wtp[i] = conv_w[(f * 3 + j) * NE + (e2 << 1) + p];
}

// ---------- kernel 2: q_emb gather + q_norm. grid = B*Q blocks of 64.
__global__ void qemb_kernel(const int* __restrict__ question, const float* __restrict__ embeds,
                            float* __restrict__ q_emb, float* __restrict__ q_norm) {
    int row = blockIdx.x;       // b*NQ + q
    int l = threadIdx.x;        // 64
    int tok = question[row];
    const float4* rp = reinterpret_cast<const float4*>(embeds + (size_t)tok * NE);
    float4* op = reinterpret_cast<float4*>(q_emb + (size_t)row * NE);
    float ss = 0.f;
    for (int g = l; g < 75; g += 64) {
        float4 v = rp[g];
        op[g] = v;
        ss += v.x * v.x + v.y * v.y + v.z * v.z + v.w * v.w;
    }
    ss = wave_reduce_sum(ss);
    if (l == 0) q_norm[row] = sqrtf(ss);
}

// ---------- kernel 3: q_conv + qc_norm. grid = B*NQ blocks of 256 (thread = f).
__global__ __launch_bounds__(256) void qconv_kernel(const float* __restrict__ q_emb,
                                                    const float* __restrict__ Wtp,
                                                    float* __restrict__ q_conv,
                                                    float* __restrict__ qc_norm) {
    __shared__ float xq[3][NE];
    __shared__ float red[4];
    int bt = blockIdx.x;        // b*NQ + t
    int b = bt >> 5, t = bt & 31;
    int tid = threadIdx.x;
    for (int idx = tid; idx < 3 * NE; idx += 256) {
        int j = idx / NE, e = idx % NE;
        int tr = t + j;
        xq[j][e] = (tr < NQ) ? q_emb[(size_t)(b * NQ + tr) * NE + e] : 0.f;
    }
    __syncthreads();
    float acc = 0.f, acc2 = 0.f;
    const float2* Wp = reinterpret_cast<const float2*>(Wtp);
    for (int e2 = 0; e2 < NE / 2; ++e2) {
        float2 w0 = Wp[(e2 * 3 + 0) * 256 + tid];
        float2 w1 = Wp[(e2 * 3 + 1) * 256 + tid];
        float2 w2 = Wp[(e2 * 3 + 2) * 256 + tid];
        int e = e2 << 1;
        acc  += xq[0][e] * w0.x + xq[1][e] * w1.x + xq[2][e] * w2.x;
        acc2 += xq[0][e + 1] * w0.y + xq[1][e + 1] * w1.y + xq[2][e + 1] * w2.y;
    }
    acc += acc2;
    q_conv[(size_t)bt * 256 + tid] = acc;
    float ss = wave_reduce_sum(acc * acc);
    if ((tid & 63) == 0) red[tid >> 6] = ss;
    __syncthreads();
    if (tid == 0) qc_norm[bt] = sqrtf(red[0] + red[1] + red[2] + red[3]);
}

// ---------- kernel 4: fused per-(b,s) block: gather s_emb, conv, cosines, pools, head.
extern __shared__ float lds[];
__global__ __launch_bounds__(256, 1) void fused_kernel(
    const int* __restrict__ sentences, const int* __restrict__ question,
    const float* __restrict__ sim_oh, const float* __restrict__ embeds,
    const float* __restrict__ Wtp,
    const float* __restrict__ q_emb, const float* __restrict__ q_norm,
    const float* __restrict__ q_conv, const float* __restrict__ qc_norm,
    const float* __restrict__ lin_w, const float* __restrict__ lin_b,
    float* __restrict__ sent_ws, float* __restrict__ d_out) {
    __shared__ int toks[NL];
    __shared__ float smaskf[NL], snorm[NL], scnorm[NL];
    __shared__ float wq[4];

    int tid = threadIdx.x;
    int lane = tid & 63;
    int w = tid >> 6;
    int bs = blockIdx.x;          // b*NS + s
    int b = bs / NS;

    if (tid < NL) {
        int tk = sentences[(size_t)bs * NL + tid];
        toks[tid] = tk;
        smaskf[tid] = (tk > 1) ? 1.f : 0.f;
    }
    __syncthreads();

    // ---- gather s_emb rows 0..63 (fp32, XOR-swizzled 16B groups), rows 64,65 zero
    for (int r = w; r < 66; r += 4) {
        if (r < NL) {
            const float4* rowp = reinterpret_cast<const float4*>(embeds + (size_t)toks[r] * NE);
            float ss = 0.f;
            for (int g = lane; g < 75; g += 64) {
                float4 v = rowp[g];
                ss += v.x * v.x + v.y * v.y + v.z * v.z + v.w * v.w;
                *reinterpret_cast<float4*>(&lds[r * EPITCH + ((g ^ (r & 7)) << 2)]) = v;
            }
            ss = wave_reduce_sum(ss);
            if (lane == 0) snorm[r] = sqrtf(ss);
        } else {
            float4 z = {0.f, 0.f, 0.f, 0.f};
            for (int g = lane; g < 75; g += 64)
                *reinterpret_cast<float4*>(&lds[r * EPITCH + ((g ^ (r & 7)) << 2)]) = z;
        }
    }
    __syncthreads();

    // ---- conv: thread owns f = tid, accumulates all 64 t in registers.
    float acc[NL];
#pragma unroll
    for (int t = 0; t < NL; ++t) acc[t] = 0.f;
    const float2* Wp = reinterpret_cast<const float2*>(Wtp);
#pragma unroll 1
    for (int e2 = 0; e2 < NE / 2; ++e2) {
        float2 x[66];
        int g4 = e2 >> 1;
        int sub = (e2 & 1) << 1;
#pragma unroll
        for (int r = 0; r < 66; ++r) {
            x[r] = *reinterpret_cast<const float2*>(
                &lds[r * EPITCH + ((g4 ^ (r & 7)) << 2) + sub]);
        }
        float2 w0 = Wp[(e2 * 3 + 0) * 256 + tid];
        float2 w1 = Wp[(e2 * 3 + 1) * 256 + tid];
        float2 w2 = Wp[(e2 * 3 + 2) * 256 + tid];
#pragma unroll
        for (int t = 0; t < NL; ++t) {
            acc[t] += x[t].x * w0.x + x[t].y * w0.y
                    + x[t + 1].x * w1.x + x[t + 1].y * w1.y
                    + x[t + 2].x * w2.x + x[t + 2].y * w2.y;
        }
    }
    // write s_conv tile to LDS (swizzled), then row norms
#pragma unroll
    for (int t = 0; t < NL; ++t) {
        lds[SCOFF + t * NF + ((((tid >> 2) ^ (t & 7)) << 2) | (tid & 3))] = acc[t];
    }
    __syncthreads();
    for (int r = w; r < NL; r += 4) {
        float ss = 0.f;
#pragma unroll
        for (int k = 0; k < 4; ++k) {
            int f = lane + (k << 6);
            float v = lds[SCOFF + r * NF + ((((f >> 2) ^ (r & 7)) << 2) | (f & 3))];
            ss += v * v;
        }
        ss = wave_reduce_sum(ss);
        if (lane == 0) scnorm[r] = sqrtf(ss);
    }
    __syncthreads();

    // ---- sims + pools + head. lane = t; wave w handles q = w + 4*qi.
    int t = lane;
    float sn = snorm[t], scn = scnorm[t], sm = smaskf[t];
    float lw0 = lin_w[0], lw1 = lin_w[1], lw2 = lin_w[2];
    float lw3 = lin_w[3], lw4 = lin_w[4], lw5 = lin_w[5];
    float lb = lin_b[0];
    float myqsum = 0.f;
    for (int qi = 0; qi < 8; ++qi) {
        int q = w + (qi << 2);
        int qrow = b * NQ + q;
        const float4* qe = reinterpret_cast<const float4*>(q_emb + (size_t)qrow * NE);
        float d0 = 0.f, d1 = 0.f, d2 = 0.f, d3 = 0.f;
#pragma unroll 5
        for (int g = 0; g < 75; ++g) {
            float4 qv = qe[g];
            float4 xv = *reinterpret_cast<const float4*>(&lds[t * EPITCH + ((g ^ (t & 7)) << 2)]);
            d0 += qv.x * xv.x; d1 += qv.y * xv.y; d2 += qv.z * xv.z; d3 += qv.w * xv.w;
        }
        float dot_ins = (d0 + d1) + (d2 + d3);
        const float4* qc = reinterpret_cast<const float4*>(q_conv + (size_t)qrow * NF);
        float c0 = 0.f, c1 = 0.f, c2 = 0.f, c3 = 0.f;
#pragma unroll 4
        for (int g = 0; g < 64; ++g) {
            float4 qv = qc[g];
            float4 xv = *reinterpret_cast<const float4*>(&lds[SCOFF + t * NF + ((g ^ (t & 7)) << 2)]);
            c0 += qv.x * xv.x; c1 += qv.y * xv.y; c2 += qv.z * xv.z; c3 += qv.w * xv.w;
        }
        float dot_sens = (c0 + c1) + (c2 + c3);

        int qtok = question[qrow];
        float qm = (qtok > 1) ? 1.f : 0.f;
        float qn = q_norm[qrow], qcn = qc_norm[qrow];
        float sim_ins = dot_ins / (qn * sn) * (qm * sm);
        float sim_sens = dot_sens / (qcn * scn);
        float oh = sim_oh[((size_t)bs * NQ + q) * NL + t];

        float f0, f1, f2, f3, f4, f5;
        top5_pool(sim_ins, lane, f0, f1);
        top5_pool(sim_sens, lane, f2, f3);
        top5_pool(oh, lane, f4, f5);
        float z = f0 * lw0 + f1 * lw1 + f2 * lw2 + f3 * lw3 + f4 * lw4 + f5 * lw5 + lb;
        float p = 1.f / (1.f + expf(-z));
        myqsum += p;      // wave-uniform
    }
    if (lane == 0) wq[w] = myqsum;
    __syncthreads();
    if (tid == 0) {
        float sent = (wq[0] + wq[1] + wq[2] + wq[3]) * (1.f / 32.f);
        sent_ws[bs] = sent;
        d_out[1 + bs] = sent;
    }
}

// ---------- kernel 5: losses + doc_emit. single block of 256.
__global__ void loss_kernel(const float* __restrict__ sent_ws, const int* __restrict__ tsent,
                            const int* __restrict__ tdoc, float* __restrict__ d_out) {
    __shared__ float red[4];
    __shared__ float dred[16];
    int tid = threadIdx.x;
    float acc = 0.f;
    for (int i = tid; i < NB * NS; i += 256) {
        float p = sent_ws[i];
        float tt = (float)tsent[i];
        acc += tt * logf(p) + (1.f - tt) * logf(1.f - p);
    }
    acc = wave_reduce_sum(acc);
    if ((tid & 63) == 0) red[tid >> 6] = acc;
    if (tid < NB) {
        float m = -3.4e38f;
        for (int s = 0; s < NS; ++s) m = fmaxf(m, sent_ws[tid * NS + s]);
        d_out[1 + NB * NS + tid] = m;
        float tt = (float)tdoc[tid];
        dred[tid] = tt * logf(m) + (1.f - tt) * logf(1.f - m);
    }
    __syncthreads();
    if (tid == 0) {
        float sal = -(red[0] + red[1] + red[2] + red[3]) / (float)(NB * NS);
        float dsum = 0.f;
        for (int i = 0; i < NB; ++i) dsum += dred[i];
        float dal = -dsum / (float)NB;
        d_out[0] = 0.5f * (sal + dal);
    }
}

extern "C" void kernel_launch(void* const* d_in, const int* in_sizes, int n_in,
                              void* d_out, int out_size, void* d_ws, size_t ws_size,
                              hipStream_t stream) {
    const int* sentences = (const int*)d_in[0];
    const int* question = (const int*)d_in[1];
    const int* tsent = (const int*)d_in[2];
    const int* tdoc = (const int*)d_in[3];
    const float* sim_oh = (const float*)d_in[4];
    const float* embeds = (const float*)d_in[5];
    const float* conv_w = (const float*)d_in[6];
    const float* lin_w = (const float*)d_in[7];
    const float* lin_b = (const float*)d_in[8];
    float* out = (float*)d_out;

    float* ws = (float*)d_ws;
    float* Wtp = ws;                         // 230400
    float* q_emb = Wtp + 230400;             // 153600
    float* q_norm = q_emb + 153600;          // 512
    float* q_conv = q_norm + 512;            // 131072
    float* qc_norm = q_conv + 131072;        // 512
    float* sent_ws = qc_norm + 512;          // 768

    hipFuncSetAttribute(reinterpret_cast<const void*>(fused_kernel),
                        hipFuncAttributeMaxDynamicSharedMemorySize, DYN_LDS);

    wtrans_kernel<<<900, 256, 0, stream>>>(conv_w, Wtp);
    qemb_kernel<<<NB * NQ, 64, 0, stream>>>(question, embeds, q_emb, q_norm);
    qconv_kernel<<<NB * NQ, 256, 0, stream>>>(q_emb, Wtp, q_conv, qc_norm);
    fused_kernel<<<NB * NS, 256, DYN_LDS, stream>>>(
        sentences, question, sim_oh, embeds, Wtp, q_emb, q_norm, q_conv, qc_norm,
        lin_w, lin_b, sent_ws, out);
    loss_kernel<<<1, 256, 0, stream>>>(sent_ws, tsent, tdoc, out);
}

// Round 2
// 224.390 us; speedup vs baseline: 5.5152x; 5.5152x over previous
//
#include <hip/hip_runtime.h>
#include <math.h>

#define NB 16
#define NS 48
#define NL 64
#define NQ 32
#define NE 300
#define NF 256
#define KP 320            // padded K for embeddings (bf16)
#define QROWS 36          // qe rows per b (32 + zero pad for taps)

typedef __attribute__((ext_vector_type(8))) short short8;
typedef __attribute__((ext_vector_type(4))) float f32x4;

#define MFMA(a,b,c) __builtin_amdgcn_mfma_f32_16x16x32_bf16((a),(b),(c),0,0,0)

__device__ __forceinline__ unsigned short f2bf(float f) {
    unsigned u = __float_as_uint(f);
    u += 0x7fff + ((u >> 16) & 1);           // RNE
    return (unsigned short)(u >> 16);
}

// dynamic-LDS byte offsets
#define SE_PITCH 640                       // 320 bf16 per row
#define SC_OFF (66 * 640)                  // 42240
#define SC_PITCH 512                       // 256 bf16 per row
#define SIMI_OFF (SC_OFF + 64 * 512)       // 75008
#define SIM_PITCH 68
#define SIMS_OFF (SIMI_OFF + 32 * SIM_PITCH * 4)   // 83712
#define DYN_LDS  (SIMS_OFF + 32 * SIM_PITCH * 4)   // 92416

__device__ __forceinline__ float wave_reduce_sum(float v) {
#pragma unroll
    for (int off = 32; off; off >>= 1) v += __shfl_xor(v, off, 64);
    return v;
}
__device__ __forceinline__ float wave_reduce_max(float v) {
#pragma unroll
    for (int off = 32; off; off >>= 1) v = fmaxf(v, __shfl_xor(v, off, 64));
    return v;
}
__device__ __forceinline__ void top5_pool(float v, int lane, float& mx, float& mn) {
    float sum = 0.f, first = 0.f;
#pragma unroll
    for (int i = 0; i < 5; ++i) {
        float m = wave_reduce_max(v);
        if (i == 0) first = m;
        sum += m;
        unsigned long long msk = __ballot(v == m);
        int leader = __ffsll(msk) - 1;
        if (lane == leader) v = -3.4e38f;
    }
    mx = first;
    mn = sum * 0.2f;
}

// ---------- pack conv_w -> Wb[j][f][k] bf16, k padded to 320 with zeros
__global__ void wb_kernel(const float* __restrict__ conv_w, unsigned short* __restrict__ Wb) {
    int i = blockIdx.x * 256 + threadIdx.x;      // 3*256*320 = 245760
    if (i >= 3 * NF * KP) return;
    int k = i % KP;
    int rest = i / KP;                           // j*256 + f
    int f = rest & 255;
    int j = rest >> 8;
    Wb[i] = (k < NE) ? f2bf(conv_w[(f * 3 + j) * NE + k]) : (unsigned short)0;
}

// ---------- q_emb gather -> bf16 [b][36][320] + q_norm (fp32 norms)
__global__ void qe_kernel(const int* __restrict__ question, const float* __restrict__ embeds,
                          unsigned short* __restrict__ qe, float* __restrict__ q_norm) {
    int row = blockIdx.x;                        // b*36 + r
    int b = row / QROWS, r = row % QROWS;
    int l = threadIdx.x;
    unsigned short* dst = qe + (size_t)row * KP;
    if (r < NQ) {
        int tok = question[b * NQ + r];
        const float4* rp = (const float4*)(embeds + (size_t)tok * NE);
        float ss;
        {
            float4 v = rp[l];
            ushort4 h = {f2bf(v.x), f2bf(v.y), f2bf(v.z), f2bf(v.w)};
            *(ushort4*)(dst + 4 * l) = h;
            ss = v.x * v.x + v.y * v.y + v.z * v.z + v.w * v.w;
        }
        if (l < 11) {
            float4 v = rp[64 + l];
            ushort4 h = {f2bf(v.x), f2bf(v.y), f2bf(v.z), f2bf(v.w)};
            *(ushort4*)(dst + 256 + 4 * l) = h;
            ss += v.x * v.x + v.y * v.y + v.z * v.z + v.w * v.w;
        }
        if (l < 5) {
            ushort4 z = {0, 0, 0, 0};
            *(ushort4*)(dst + 300 + 4 * l) = z;
        }
        ss = wave_reduce_sum(ss);
        if (l == 0) q_norm[b * NQ + r] = sqrtf(ss);
    } else {
        ushort4 z = {0, 0, 0, 0};
        *(ushort4*)(dst + 4 * l) = z;
        if (l < 16) *(ushort4*)(dst + 256 + 4 * l) = z;
    }
}

// ---------- q_conv via MFMA: per b, M=32 N=256 K=3x320. Output bf16 + fp32 norms.
__global__ __launch_bounds__(256) void qconv_mfma_kernel(
        const unsigned short* __restrict__ qe, const unsigned short* __restrict__ Wb,
        unsigned short* __restrict__ q_conv, float* __restrict__ qc_norm) {
    __shared__ float part[4][NQ];
    int b = blockIdx.x;
    int tid = threadIdx.x, lane = tid & 63, w = tid >> 6;
    int rl = lane & 15, kg = lane >> 4;
    f32x4 acc[2][4];
#pragma unroll
    for (int m = 0; m < 2; ++m)
#pragma unroll
        for (int nn = 0; nn < 4; ++nn) acc[m][nn] = (f32x4){0.f, 0.f, 0.f, 0.f};

    for (int j = 0; j < 3; ++j) {
        for (int ks = 0; ks < 10; ++ks) {
            int k = ks * 32 + kg * 8;
            short8 a0 = *(const short8*)(qe + ((size_t)(b * QROWS) + rl + j) * KP + k);
            short8 a1 = *(const short8*)(qe + ((size_t)(b * QROWS) + 16 + rl + j) * KP + k);
#pragma unroll
            for (int nn = 0; nn < 4; ++nn) {
                int f = ((w << 2) + nn) * 16 + rl;
                short8 bb = *(const short8*)(Wb + (size_t)(j * NF + f) * KP + k);
                acc[0][nn] = MFMA(a0, bb, acc[0][nn]);
                acc[1][nn] = MFMA(a1, bb, acc[1][nn]);
            }
        }
    }
    float s[2][4];
#pragma unroll
    for (int m = 0; m < 2; ++m)
#pragma unroll
        for (int reg = 0; reg < 4; ++reg) s[m][reg] = 0.f;
#pragma unroll
    for (int m = 0; m < 2; ++m)
#pragma unroll
        for (int nn = 0; nn < 4; ++nn)
#pragma unroll
            for (int reg = 0; reg < 4; ++reg) {
                float v = acc[m][nn][reg];
                int q = m * 16 + kg * 4 + reg;
                int f = ((w << 2) + nn) * 16 + rl;
                q_conv[((size_t)(b * NQ) + q) * NF + f] = f2bf(v);
                s[m][reg] += v * v;
            }
#pragma unroll
    for (int m = 0; m < 2; ++m)
#pragma unroll
        for (int reg = 0; reg < 4; ++reg) {
            float v = s[m][reg];
            v += __shfl_xor(v, 1, 64); v += __shfl_xor(v, 2, 64);
            v += __shfl_xor(v, 4, 64); v += __shfl_xor(v, 8, 64);
            if (rl == 0) part[w][m * 16 + kg * 4 + reg] = v;
        }
    __syncthreads();
    if (tid < NQ) qc_norm[b * NQ + tid] =
        sqrtf(part[0][tid] + part[1][tid] + part[2][tid] + part[3][tid]);
}

// ---------- fused per-(b,s): gather -> conv MFMA -> sims MFMA -> pool/head
extern __shared__ char ldsc[];
__global__ __launch_bounds__(256, 1) void fused2_kernel(
    const int* __restrict__ sentences, const int* __restrict__ question,
    const float* __restrict__ sim_oh, const float* __restrict__ embeds,
    const unsigned short* __restrict__ Wb,
    const unsigned short* __restrict__ qe, const float* __restrict__ q_norm,
    const unsigned short* __restrict__ q_conv, const float* __restrict__ qc_norm,
    const float* __restrict__ lin_w, const float* __restrict__ lin_b,
    float* __restrict__ sent_ws, float* __restrict__ d_out)
{
    __shared__ int toks[NL];
    __shared__ float smaskf[NL], snorm[NL], scnorm[NL];
    __shared__ float qn_s[NQ], qcn_s[NQ], qmf_s[NQ];
    __shared__ float scpart[4][NL];
    __shared__ float wq[4];

    int tid = threadIdx.x, lane = tid & 63, w = tid >> 6;
    int rl = lane & 15, kg = lane >> 4;
    int bs = blockIdx.x, b = bs / NS;

    if (tid < NL) {
        int tk = sentences[(size_t)bs * NL + tid];
        toks[tid] = tk;
        smaskf[tid] = (tk > 1) ? 1.f : 0.f;
    } else if (tid < NL + NQ) {
        int q = tid - NL;
        qn_s[q] = q_norm[b * NQ + q];
    } else if (tid < NL + 2 * NQ) {
        int q = tid - NL - NQ;
        qcn_s[q] = qc_norm[b * NQ + q];
    } else if (tid < NL + 3 * NQ) {
        int q = tid - NL - 2 * NQ;
        qmf_s[q] = (question[b * NQ + q] > 1) ? 1.f : 0.f;
    }
    __syncthreads();

    // ---- Phase 1: gather s_emb -> LDS bf16 (16B-granule XOR swizzle) + snorm
    for (int r = w; r < 66; r += 4) {
        if (r < NL) {
            const float4* rp = (const float4*)(embeds + (size_t)toks[r] * NE);
            char* rowbase = ldsc + r * SE_PITCH;
            int m7 = r & 7;
            float ss;
            {
                float4 v = rp[lane];
                ushort4 h = {f2bf(v.x), f2bf(v.y), f2bf(v.z), f2bf(v.w)};
                *(ushort4*)(rowbase + (((lane >> 1) ^ m7) << 4) + ((lane & 1) << 3)) = h;
                ss = v.x * v.x + v.y * v.y + v.z * v.z + v.w * v.w;
            }
            if (lane < 11) {
                float4 v = rp[64 + lane];
                ushort4 h = {f2bf(v.x), f2bf(v.y), f2bf(v.z), f2bf(v.w)};
                int g = 64 + lane;
                *(ushort4*)(rowbase + (((g >> 1) ^ m7) << 4) + ((g & 1) << 3)) = h;
                ss += v.x * v.x + v.y * v.y + v.z * v.z + v.w * v.w;
            }
            if (lane < 5) {
                int pk = 37 + ((lane + 1) >> 1);
                int sub = ((lane + 1) & 1) << 3;
                *(unsigned long long*)(rowbase + ((pk ^ m7) << 4) + sub) = 0ull;
            }
            ss = wave_reduce_sum(ss);
            if (lane == 0) snorm[r] = sqrtf(ss);
        } else {
            if (lane < 40) {
                uint4 z = {0, 0, 0, 0};
                *(uint4*)(ldsc + r * SE_PITCH + ((lane ^ (r & 7)) << 4)) = z;
            }
        }
    }
    __syncthreads();

    // ---- Phase 2: conv MFMA. wave w owns f-tiles w*4..w*4+3, all 4 t-tiles.
    {
        f32x4 acc[4][4];
#pragma unroll
        for (int m = 0; m < 4; ++m)
#pragma unroll
            for (int nn = 0; nn < 4; ++nn) acc[m][nn] = (f32x4){0.f, 0.f, 0.f, 0.f};

        for (int j = 0; j < 3; ++j) {
            for (int ks = 0; ks < 10; ++ks) {
                int k = ks * 32 + kg * 8;
                short8 a[4], bb[4];
#pragma unroll
                for (int m = 0; m < 4; ++m) {
                    int row = m * 16 + rl + j;
                    a[m] = *(const short8*)(ldsc + row * SE_PITCH +
                                            ((((ks << 2) + kg) ^ (row & 7)) << 4));
                }
#pragma unroll
                for (int nn = 0; nn < 4; ++nn) {
                    int f = ((w << 2) + nn) * 16 + rl;
                    bb[nn] = *(const short8*)(Wb + (size_t)(j * NF + f) * KP + k);
                }
#pragma unroll
                for (int m = 0; m < 4; ++m)
#pragma unroll
                    for (int nn = 0; nn < 4; ++nn)
                        acc[m][nn] = MFMA(a[m], bb[nn], acc[m][nn]);
            }
        }
        float s[4][4];
#pragma unroll
        for (int m = 0; m < 4; ++m)
#pragma unroll
            for (int reg = 0; reg < 4; ++reg) s[m][reg] = 0.f;
#pragma unroll
        for (int m = 0; m < 4; ++m)
#pragma unroll
            for (int nn = 0; nn < 4; ++nn) {
                int f = ((w << 2) + nn) * 16 + rl;
#pragma unroll
                for (int reg = 0; reg < 4; ++reg) {
                    float v = acc[m][nn][reg];
                    int t = m * 16 + kg * 4 + reg;
                    *(unsigned short*)(ldsc + SC_OFF + t * SC_PITCH +
                                       (((f >> 3) ^ (t & 7)) << 4) + ((f & 7) << 1)) = f2bf(v);
                    s[m][reg] += v * v;
                }
            }
#pragma unroll
        for (int m = 0; m < 4; ++m)
#pragma unroll
            for (int reg = 0; reg < 4; ++reg) {
                float v = s[m][reg];
                v += __shfl_xor(v, 1, 64); v += __shfl_xor(v, 2, 64);
                v += __shfl_xor(v, 4, 64); v += __shfl_xor(v, 8, 64);
                if (rl == 0) scpart[w][m * 16 + kg * 4 + reg] = v;
            }
    }
    __syncthreads();
    if (tid < NL)
        scnorm[tid] = sqrtf(scpart[0][tid] + scpart[1][tid] + scpart[2][tid] + scpart[3][tid]);

    // ---- Phase B: sim_ins MFMA (M=32 q, N=16 t per wave, K=320)
    {
        f32x4 acc[2];
        acc[0] = (f32x4){0.f, 0.f, 0.f, 0.f};
        acc[1] = (f32x4){0.f, 0.f, 0.f, 0.f};
        int t = (w << 4) + rl, t7 = t & 7;
        for (int ks = 0; ks < 10; ++ks) {
            int k = ks * 32 + kg * 8;
            short8 bB = *(const short8*)(ldsc + t * SE_PITCH + ((((ks << 2) + kg) ^ t7) << 4));
            short8 a0 = *(const short8*)(qe + (size_t)(b * QROWS + rl) * KP + k);
            short8 a1 = *(const short8*)(qe + (size_t)(b * QROWS + 16 + rl) * KP + k);
            acc[0] = MFMA(a0, bB, acc[0]);
            acc[1] = MFMA(a1, bB, acc[1]);
        }
        float sn_t = snorm[t], sm_t = smaskf[t];
#pragma unroll
        for (int m = 0; m < 2; ++m)
#pragma unroll
            for (int reg = 0; reg < 4; ++reg) {
                int q = m * 16 + kg * 4 + reg;
                float sim = acc[m][reg] / (qn_s[q] * sn_t) * (qmf_s[q] * sm_t);
                *(float*)(ldsc + SIMI_OFF + (q * SIM_PITCH + t) * 4) = sim;
            }
    }
    __syncthreads();

    // ---- Phase C: sim_sens MFMA (K=256)
    {
        f32x4 acc[2];
        acc[0] = (f32x4){0.f, 0.f, 0.f, 0.f};
        acc[1] = (f32x4){0.f, 0.f, 0.f, 0.f};
        int t = (w << 4) + rl, t7 = t & 7;
        for (int ks = 0; ks < 8; ++ks) {
            int k = ks * 32 + kg * 8;
            short8 bB = *(const short8*)(ldsc + SC_OFF + t * SC_PITCH +
                                         ((((ks << 2) + kg) ^ t7) << 4));
            short8 a0 = *(const short8*)(q_conv + (size_t)(b * NQ + rl) * NF + k);
            short8 a1 = *(const short8*)(q_conv + (size_t)(b * NQ + 16 + rl) * NF + k);
            acc[0] = MFMA(a0, bB, acc[0]);
            acc[1] = MFMA(a1, bB, acc[1]);
        }
        float scn_t = scnorm[t];
#pragma unroll
        for (int m = 0; m < 2; ++m)
#pragma unroll
            for (int reg = 0; reg < 4; ++reg) {
                int q = m * 16 + kg * 4 + reg;
                float sim = acc[m][reg] / (qcn_s[q] * scn_t);
                *(float*)(ldsc + SIMS_OFF + (q * SIM_PITCH + t) * 4) = sim;
            }
    }
    __syncthreads();

    // ---- Phase D: pools + head. wave w handles q = w*8 .. w*8+7, lane = t.
    {
        float lw0 = lin_w[0], lw1 = lin_w[1], lw2 = lin_w[2];
        float lw3 = lin_w[3], lw4 = lin_w[4], lw5 = lin_w[5];
        float lb = lin_b[0];
        float psum = 0.f;
        for (int qi = 0; qi < 8; ++qi) {
            int q = (w << 3) + qi;
            float si = *(float*)(ldsc + SIMI_OFF + (q * SIM_PITCH + lane) * 4);
            float sv = *(float*)(ldsc + SIMS_OFF + (q * SIM_PITCH + lane) * 4);
            float oh = sim_oh[((size_t)bs * NQ + q) * NL + lane];
            float f0, f1, f2, f3, f4, f5;
            top5_pool(si, lane, f0, f1);
            top5_pool(sv, lane, f2, f3);
            top5_pool(oh, lane, f4, f5);
            float z = f0 * lw0 + f1 * lw1 + f2 * lw2 + f3 * lw3 + f4 * lw4 + f5 * lw5 + lb;
            psum += 1.f / (1.f + expf(-z));
        }
        if (lane == 0) wq[w] = psum;
    }
    __syncthreads();
    if (tid == 0) {
        float sent = (wq[0] + wq[1] + wq[2] + wq[3]) * (1.f / 32.f);
        sent_ws[bs] = sent;
        d_out[1 + bs] = sent;
    }
}

// ---------- losses + doc_emit
__global__ void loss_kernel(const float* __restrict__ sent_ws, const int* __restrict__ tsent,
                            const int* __restrict__ tdoc, float* __restrict__ d_out) {
    __shared__ float red[4];
    __shared__ float dred[16];
    int tid = threadIdx.x;
    float acc = 0.f;
    for (int i = tid; i < NB * NS; i += 256) {
        float p = sent_ws[i];
        float tt = (float)tsent[i];
        acc += tt * logf(p) + (1.f - tt) * logf(1.f - p);
    }
    acc = wave_reduce_sum(acc);
    if ((tid & 63) == 0) red[tid >> 6] = acc;
    if (tid < NB) {
        float m = -3.4e38f;
        for (int s = 0; s < NS; ++s) m = fmaxf(m, sent_ws[tid * NS + s]);
        d_out[1 + NB * NS + tid] = m;
        float tt = (float)tdoc[tid];
        dred[tid] = tt * logf(m) + (1.f - tt) * logf(1.f - m);
    }
    __syncthreads();
    if (tid == 0) {
        float sal = -(red[0] + red[1] + red[2] + red[3]) / (float)(NB * NS);
        float dsum = 0.f;
        for (int i = 0; i < NB; ++i) dsum += dred[i];
        float dal = -dsum / (float)NB;
        d_out[0] = 0.5f * (sal + dal);
    }
}

extern "C" void kernel_launch(void* const* d_in, const int* in_sizes, int n_in,
                              void* d_out, int out_size, void* d_ws, size_t ws_size,
                              hipStream_t stream) {
    const int* sentences = (const int*)d_in[0];
    const int* question = (const int*)d_in[1];
    const int* tsent = (const int*)d_in[2];
    const int* tdoc = (const int*)d_in[3];
    const float* sim_oh = (const float*)d_in[4];
    const float* embeds = (const float*)d_in[5];
    const float* conv_w = (const float*)d_in[6];
    const float* lin_w = (const float*)d_in[7];
    const float* lin_b = (const float*)d_in[8];
    float* out = (float*)d_out;

    char* wsc = (char*)d_ws;
    unsigned short* Wb     = (unsigned short*)(wsc);             // 491520 B
    unsigned short* qe     = (unsigned short*)(wsc + 491520);    // 368640 B
    float* q_norm          = (float*)(wsc + 860160);             // 2048 B
    unsigned short* q_conv = (unsigned short*)(wsc + 862208);    // 262144 B
    float* qc_norm         = (float*)(wsc + 1124352);            // 2048 B
    float* sent_ws         = (float*)(wsc + 1126400);            // 3072 B

    hipFuncSetAttribute(reinterpret_cast<const void*>(fused2_kernel),
                        hipFuncAttributeMaxDynamicSharedMemorySize, DYN_LDS);

    wb_kernel<<<960, 256, 0, stream>>>(conv_w, Wb);
    qe_kernel<<<NB * QROWS, 64, 0, stream>>>(question, embeds, qe, q_norm);
    qconv_mfma_kernel<<<NB, 256, 0, stream>>>(qe, Wb, q_conv, qc_norm);
    fused2_kernel<<<NB * NS, 256, DYN_LDS, stream>>>(
        sentences, question, sim_oh, embeds, Wb, qe, q_norm, q_conv, qc_norm,
        lin_w, lin_b, sent_ws, out);
    loss_kernel<<<1, 256, 0, stream>>>(sent_ws, tsent, tdoc, out);
}

// Round 3
// 153.326 us; speedup vs baseline: 8.0714x; 1.4635x over previous
//
#include <hip/hip_runtime.h>
#include <math.h>

#define NB 16
#define NS 48
#define NL 64
#define NQ 32
#define NE 300
#define NF 256
#define KP 320            // padded K for embeddings (bf16)
#define QROWS 36          // qe rows per b (32 + zero pad for taps)

typedef __attribute__((ext_vector_type(8))) short short8;
typedef __attribute__((ext_vector_type(4))) float f32x4;

#define MFMA(a,b,c) __builtin_amdgcn_mfma_f32_16x16x32_bf16((a),(b),(c),0,0,0)

__device__ __forceinline__ unsigned short f2bf(float f) {
    unsigned u = __float_as_uint(f);
    u += 0x7fff + ((u >> 16) & 1);           // RNE
    return (unsigned short)(u >> 16);
}

// dynamic-LDS byte offsets (s_conv region overlays s_emb region after reorder)
#define SE_PITCH 640                        // 320 bf16 per row, 66 rows
#define SC_PITCH 512                        // 256 bf16 per row, 64 rows (overlay)
#define SIM_OFF (66 * 640)                  // 42240
#define SIM_PITCH 66                        // floats per q-row
#define DYN_LDS (SIM_OFF + NQ * SIM_PITCH * 4)   // 50688 bytes

__device__ __forceinline__ float wave_reduce_sum(float v) {
#pragma unroll
    for (int off = 32; off; off >>= 1) v += __shfl_xor(v, off, 64);
    return v;
}
__device__ __forceinline__ float wave_reduce_max(float v) {
#pragma unroll
    for (int off = 32; off; off >>= 1) v = fmaxf(v, __shfl_xor(v, off, 64));
    return v;
}
__device__ __forceinline__ void top5_pool(float v, int lane, float& mx, float& mn) {
    float sum = 0.f, first = 0.f;
#pragma unroll
    for (int i = 0; i < 5; ++i) {
        float m = wave_reduce_max(v);
        if (i == 0) first = m;
        sum += m;
        unsigned long long msk = __ballot(v == m);
        int leader = __ffsll(msk) - 1;
        if (lane == leader) v = -3.4e38f;
    }
    mx = first;
    mn = sum * 0.2f;
}

// ---------- pack conv_w -> Wb[j][f][k] bf16, k padded to 320; also reset done ctr
__global__ void wb_kernel(const float* __restrict__ conv_w, unsigned short* __restrict__ Wb,
                          unsigned int* __restrict__ done_ctr) {
    if (blockIdx.x == 0 && threadIdx.x == 0) done_ctr[0] = 0u;
    int i = blockIdx.x * 256 + threadIdx.x;      // 3*256*320 = 245760
    if (i >= 3 * NF * KP) return;
    int k = i % KP;
    int rest = i / KP;                           // j*256 + f
    int f = rest & 255;
    int j = rest >> 8;
    Wb[i] = (k < NE) ? f2bf(conv_w[(f * 3 + j) * NE + k]) : (unsigned short)0;
}

// ---------- q_emb gather -> bf16 [b][36][320] + q_norm
__global__ void qe_kernel(const int* __restrict__ question, const float* __restrict__ embeds,
                          unsigned short* __restrict__ qe, float* __restrict__ q_norm) {
    int row = blockIdx.x;                        // b*36 + r
    int b = row / QROWS, r = row % QROWS;
    int l = threadIdx.x;
    unsigned short* dst = qe + (size_t)row * KP;
    if (r < NQ) {
        int tok = question[b * NQ + r];
        const float4* rp = (const float4*)(embeds + (size_t)tok * NE);
        float ss;
        {
            float4 v = rp[l];
            ushort4 h = {f2bf(v.x), f2bf(v.y), f2bf(v.z), f2bf(v.w)};
            *(ushort4*)(dst + 4 * l) = h;
            ss = v.x * v.x + v.y * v.y + v.z * v.z + v.w * v.w;
        }
        if (l < 11) {
            float4 v = rp[64 + l];
            ushort4 h = {f2bf(v.x), f2bf(v.y), f2bf(v.z), f2bf(v.w)};
            *(ushort4*)(dst + 256 + 4 * l) = h;
            ss += v.x * v.x + v.y * v.y + v.z * v.z + v.w * v.w;
        }
        if (l < 5) {
            ushort4 z = {0, 0, 0, 0};
            *(ushort4*)(dst + 300 + 4 * l) = z;
        }
        ss = wave_reduce_sum(ss);
        if (l == 0) q_norm[b * NQ + r] = sqrtf(ss);
    } else {
        ushort4 z = {0, 0, 0, 0};
        *(ushort4*)(dst + 4 * l) = z;
        if (l < 16) *(ushort4*)(dst + 256 + 4 * l) = z;
    }
}

// ---------- q_conv via MFMA: per b, M=32 N=256 K=3x320. Output bf16 + norms.
__global__ __launch_bounds__(256) void qconv_mfma_kernel(
        const unsigned short* __restrict__ qe, const unsigned short* __restrict__ Wb,
        unsigned short* __restrict__ q_conv, float* __restrict__ qc_norm) {
    __shared__ float part[4][NQ];
    int b = blockIdx.x;
    int tid = threadIdx.x, lane = tid & 63, w = tid >> 6;
    int rl = lane & 15, kg = lane >> 4;
    f32x4 acc[2][4];
#pragma unroll
    for (int m = 0; m < 2; ++m)
#pragma unroll
        for (int nn = 0; nn < 4; ++nn) acc[m][nn] = (f32x4){0.f, 0.f, 0.f, 0.f};

    for (int j = 0; j < 3; ++j) {
        for (int ks = 0; ks < 10; ++ks) {
            int k = ks * 32 + kg * 8;
            short8 a0 = *(const short8*)(qe + ((size_t)(b * QROWS) + rl + j) * KP + k);
            short8 a1 = *(const short8*)(qe + ((size_t)(b * QROWS) + 16 + rl + j) * KP + k);
#pragma unroll
            for (int nn = 0; nn < 4; ++nn) {
                int f = ((w << 2) + nn) * 16 + rl;
                short8 bb = *(const short8*)(Wb + (size_t)(j * NF + f) * KP + k);
                acc[0][nn] = MFMA(a0, bb, acc[0][nn]);
                acc[1][nn] = MFMA(a1, bb, acc[1][nn]);
            }
        }
    }
    float s[2][4];
#pragma unroll
    for (int m = 0; m < 2; ++m)
#pragma unroll
        for (int reg = 0; reg < 4; ++reg) s[m][reg] = 0.f;
#pragma unroll
    for (int m = 0; m < 2; ++m)
#pragma unroll
        for (int nn = 0; nn < 4; ++nn)
#pragma unroll
            for (int reg = 0; reg < 4; ++reg) {
                float v = acc[m][nn][reg];
                int q = m * 16 + kg * 4 + reg;
                int f = ((w << 2) + nn) * 16 + rl;
                q_conv[((size_t)(b * NQ) + q) * NF + f] = f2bf(v);
                s[m][reg] += v * v;
            }
#pragma unroll
    for (int m = 0; m < 2; ++m)
#pragma unroll
        for (int reg = 0; reg < 4; ++reg) {
            float v = s[m][reg];
            v += __shfl_xor(v, 1, 64); v += __shfl_xor(v, 2, 64);
            v += __shfl_xor(v, 4, 64); v += __shfl_xor(v, 8, 64);
            if (rl == 0) part[w][m * 16 + kg * 4 + reg] = v;
        }
    __syncthreads();
    if (tid < NQ) qc_norm[b * NQ + tid] =
        sqrtf(part[0][tid] + part[1][tid] + part[2][tid] + part[3][tid]);
}

// ---------- fused per-(b,s): gather -> sim_ins -> pool_ins/conv -> s_conv -> sim_sens -> head
extern __shared__ char ldsc[];
__global__ __launch_bounds__(256, 3) void fused3_kernel(
    const int* __restrict__ sentences, const int* __restrict__ question,
    const float* __restrict__ sim_oh, const float* __restrict__ embeds,
    const unsigned short* __restrict__ Wb,
    const unsigned short* __restrict__ qe, const float* __restrict__ q_norm,
    const unsigned short* __restrict__ q_conv, const float* __restrict__ qc_norm,
    const float* __restrict__ lin_w, const float* __restrict__ lin_b,
    const int* __restrict__ tsent, const int* __restrict__ tdoc,
    unsigned int* __restrict__ done_ctr,
    float* __restrict__ sent_ws, float* __restrict__ d_out)
{
    __shared__ int toks[NL];
    __shared__ float smaskf[NL];
    __shared__ float qn_s[NQ], qcn_s[NQ], qmf_s[NQ];
    __shared__ float scpart[4][NL];
    __shared__ float wq[4];
    __shared__ float fpool[NQ][2];
    __shared__ int lastflag;
    __shared__ float red2[4];
    __shared__ float dred[NB];

    int tid = threadIdx.x, lane = tid & 63, w = tid >> 6;
    int rl = lane & 15, kg = lane >> 4;
    int bs = blockIdx.x, b = bs / NS;

    // ---- header loads
    if (tid < NL) {
        int tk = sentences[(size_t)bs * NL + tid];
        toks[tid] = tk;
        smaskf[tid] = (tk > 1) ? 1.f : 0.f;
    } else if (tid < NL + NQ) {
        int q = tid - NL;
        qn_s[q] = q_norm[b * NQ + q];
    } else if (tid < NL + 2 * NQ) {
        int q = tid - NL - NQ;
        qcn_s[q] = qc_norm[b * NQ + q];
    } else if (tid < NL + 3 * NQ) {
        int q = tid - NL - 2 * NQ;
        qmf_s[q] = (question[b * NQ + q] > 1) ? 1.f : 0.f;
    }
    __syncthreads();

    // ---- Phase 1: gather s_emb -> LDS bf16 (16B-granule XOR swizzle), STORES ONLY
    for (int r = w; r < 66; r += 4) {
        char* rowbase = ldsc + r * SE_PITCH;
        int m7 = r & 7;
        if (r < NL) {
            const float4* rp = (const float4*)(embeds + (size_t)toks[r] * NE);
            {
                float4 v = rp[lane];
                ushort4 h = {f2bf(v.x), f2bf(v.y), f2bf(v.z), f2bf(v.w)};
                *(ushort4*)(rowbase + (((lane >> 1) ^ m7) << 4) + ((lane & 1) << 3)) = h;
            }
            if (lane < 11) {
                float4 v = rp[64 + lane];
                ushort4 h = {f2bf(v.x), f2bf(v.y), f2bf(v.z), f2bf(v.w)};
                int g = 64 + lane;
                *(ushort4*)(rowbase + (((g >> 1) ^ m7) << 4) + ((g & 1) << 3)) = h;
            }
            if (lane < 5) {
                int pk = 37 + ((lane + 1) >> 1);
                int sub = ((lane + 1) & 1) << 3;
                *(unsigned long long*)(rowbase + ((pk ^ m7) << 4) + sub) = 0ull;
            }
        } else {
            if (lane < 40) {
                uint4 z = {0, 0, 0, 0};
                *(uint4*)(rowbase + (lane << 4)) = z;
            }
        }
    }
    __syncthreads();

    // ---- Phase 2a: snorm for my wave's t-range (rows w*16..w*16+15), kept in regs
    float my_sn = 1.f;
#pragma unroll 4
    for (int i = 0; i < 16; ++i) {
        int r = (w << 4) + i;
        float ss = 0.f;
        if (lane < 40) {
            uint4 v = *(const uint4*)(ldsc + r * SE_PITCH + ((lane ^ (r & 7)) << 4));
            float a0 = __uint_as_float(v.x << 16), a1 = __uint_as_float(v.x & 0xffff0000u);
            float a2 = __uint_as_float(v.y << 16), a3 = __uint_as_float(v.y & 0xffff0000u);
            float a4 = __uint_as_float(v.z << 16), a5 = __uint_as_float(v.z & 0xffff0000u);
            float a6 = __uint_as_float(v.w << 16), a7 = __uint_as_float(v.w & 0xffff0000u);
            ss = a0*a0 + a1*a1 + a2*a2 + a3*a3 + a4*a4 + a5*a5 + a6*a6 + a7*a7;
        }
        ss = wave_reduce_sum(ss);
        if (rl == i) my_sn = sqrtf(ss);
    }

    // ---- Phase 2b: sim_ins MFMA (M=32 q, N=16 t per wave, K=320) -> SIM buffer
    {
        f32x4 acc[2];
        acc[0] = (f32x4){0.f, 0.f, 0.f, 0.f};
        acc[1] = (f32x4){0.f, 0.f, 0.f, 0.f};
        int t = (w << 4) + rl, t7 = t & 7;
        for (int ks = 0; ks < 10; ++ks) {
            int k = ks * 32 + kg * 8;
            short8 bB = *(const short8*)(ldsc + t * SE_PITCH + ((((ks << 2) + kg) ^ t7) << 4));
            short8 a0 = *(const short8*)(qe + (size_t)(b * QROWS + rl) * KP + k);
            short8 a1 = *(const short8*)(qe + (size_t)(b * QROWS + 16 + rl) * KP + k);
            acc[0] = MFMA(a0, bB, acc[0]);
            acc[1] = MFMA(a1, bB, acc[1]);
        }
        float sm_t = smaskf[t];
        float inv_sn = sm_t / my_sn;
#pragma unroll
        for (int m = 0; m < 2; ++m)
#pragma unroll
            for (int reg = 0; reg < 4; ++reg) {
                int q = m * 16 + kg * 4 + reg;
                float sim = acc[m][reg] / qn_s[q] * inv_sn * qmf_s[q];
                *(float*)(ldsc + SIM_OFF + (q * SIM_PITCH + t) * 4) = sim;
            }
    }
    __syncthreads();

    // ---- Phase 3: pool sim_ins (wave w owns q = w*8..w*8+7, lane = t)
    {
        for (int qi = 0; qi < 8; ++qi) {
            int q = (w << 3) + qi;
            float si = *(float*)(ldsc + SIM_OFF + (q * SIM_PITCH + lane) * 4);
            float f0, f1;
            top5_pool(si, lane, f0, f1);
            if (lane == 0) { fpool[q][0] = f0; fpool[q][1] = f1; }
        }
    }

    // ---- Phase 4: conv MFMA (reads s_emb). wave w owns f-tiles w*4..w*4+3.
    f32x4 acc[4][4];
#pragma unroll
    for (int m = 0; m < 4; ++m)
#pragma unroll
        for (int nn = 0; nn < 4; ++nn) acc[m][nn] = (f32x4){0.f, 0.f, 0.f, 0.f};
    for (int j = 0; j < 3; ++j) {
        for (int ks = 0; ks < 10; ++ks) {
            int k = ks * 32 + kg * 8;
            short8 a[4], bb[4];
#pragma unroll
            for (int m = 0; m < 4; ++m) {
                int row = m * 16 + rl + j;
                a[m] = *(const short8*)(ldsc + row * SE_PITCH +
                                        ((((ks << 2) + kg) ^ (row & 7)) << 4));
            }
#pragma unroll
            for (int nn = 0; nn < 4; ++nn) {
                int f = ((w << 2) + nn) * 16 + rl;
                bb[nn] = *(const short8*)(Wb + (size_t)(j * NF + f) * KP + k);
            }
#pragma unroll
            for (int m = 0; m < 4; ++m)
#pragma unroll
                for (int nn = 0; nn < 4; ++nn)
                    acc[m][nn] = MFMA(a[m], bb[nn], acc[m][nn]);
        }
    }
    __syncthreads();   // all s_emb reads done; s_conv may overwrite

    // ---- Phase 5: write s_conv bf16 into (former s_emb) region + scpart
    {
        float s[4][4];
#pragma unroll
        for (int m = 0; m < 4; ++m)
#pragma unroll
            for (int reg = 0; reg < 4; ++reg) s[m][reg] = 0.f;
#pragma unroll
        for (int m = 0; m < 4; ++m)
#pragma unroll
            for (int nn = 0; nn < 4; ++nn) {
                int f = ((w << 2) + nn) * 16 + rl;
#pragma unroll
                for (int reg = 0; reg < 4; ++reg) {
                    float v = acc[m][nn][reg];
                    int t = m * 16 + kg * 4 + reg;
                    *(unsigned short*)(ldsc + t * SC_PITCH +
                                       (((f >> 3) ^ (t & 7)) << 4) + ((f & 7) << 1)) = f2bf(v);
                    s[m][reg] += v * v;
                }
            }
#pragma unroll
        for (int m = 0; m < 4; ++m)
#pragma unroll
            for (int reg = 0; reg < 4; ++reg) {
                float v = s[m][reg];
                v += __shfl_xor(v, 1, 64); v += __shfl_xor(v, 2, 64);
                v += __shfl_xor(v, 4, 64); v += __shfl_xor(v, 8, 64);
                if (rl == 0) scpart[w][m * 16 + kg * 4 + reg] = v;
            }
    }
    __syncthreads();

    // ---- Phase 6: prefetch oh; sim_sens MFMA (K=256) -> SIM buffer (reuse)
    float oh[8];
#pragma unroll
    for (int qi = 0; qi < 8; ++qi) {
        int q = (w << 3) + qi;
        oh[qi] = sim_oh[((size_t)bs * NQ + q) * NL + lane];
    }
    {
        f32x4 acc2[2];
        acc2[0] = (f32x4){0.f, 0.f, 0.f, 0.f};
        acc2[1] = (f32x4){0.f, 0.f, 0.f, 0.f};
        int t = (w << 4) + rl, t7 = t & 7;
        for (int ks = 0; ks < 8; ++ks) {
            int k = ks * 32 + kg * 8;
            short8 bB = *(const short8*)(ldsc + t * SC_PITCH + ((((ks << 2) + kg) ^ t7) << 4));
            short8 a0 = *(const short8*)(q_conv + (size_t)(b * NQ + rl) * NF + k);
            short8 a1 = *(const short8*)(q_conv + (size_t)(b * NQ + 16 + rl) * NF + k);
            acc2[0] = MFMA(a0, bB, acc2[0]);
            acc2[1] = MFMA(a1, bB, acc2[1]);
        }
        float scn_t = sqrtf(scpart[0][t] + scpart[1][t] + scpart[2][t] + scpart[3][t]);
        float inv_scn = 1.f / scn_t;
#pragma unroll
        for (int m = 0; m < 2; ++m)
#pragma unroll
            for (int reg = 0; reg < 4; ++reg) {
                int q = m * 16 + kg * 4 + reg;
                float sim = acc2[m][reg] / qcn_s[q] * inv_scn;
                *(float*)(ldsc + SIM_OFF + (q * SIM_PITCH + t) * 4) = sim;
            }
    }
    __syncthreads();

    // ---- Phase 7: pool sens + oh + head
    {
        float lw0 = lin_w[0], lw1 = lin_w[1], lw2 = lin_w[2];
        float lw3 = lin_w[3], lw4 = lin_w[4], lw5 = lin_w[5];
        float lb = lin_b[0];
        float psum = 0.f;
        for (int qi = 0; qi < 8; ++qi) {
            int q = (w << 3) + qi;
            float sv = *(float*)(ldsc + SIM_OFF + (q * SIM_PITCH + lane) * 4);
            float f2, f3, f4, f5;
            top5_pool(sv, lane, f2, f3);
            top5_pool(oh[qi], lane, f4, f5);
            float f0 = fpool[q][0], f1 = fpool[q][1];
            float z = f0 * lw0 + f1 * lw1 + f2 * lw2 + f3 * lw3 + f4 * lw4 + f5 * lw5 + lb;
            psum += 1.f / (1.f + expf(-z));
        }
        if (lane == 0) wq[w] = psum;
    }
    __syncthreads();
    if (tid == 0) {
        float sent = (wq[0] + wq[1] + wq[2] + wq[3]) * (1.f / 32.f);
        __hip_atomic_store(&sent_ws[bs], sent, __ATOMIC_RELEASE, __HIP_MEMORY_SCOPE_AGENT);
        d_out[1 + bs] = sent;
        unsigned old = atomicAdd(done_ctr, 1u);
        lastflag = (old == (unsigned)(NB * NS - 1)) ? 1 : 0;
    }
    __syncthreads();

    // ---- last block computes losses + doc_emit
    if (lastflag) {
        float acc_l = 0.f;
        for (int i = tid; i < NB * NS; i += 256) {
            float p = __hip_atomic_load(&sent_ws[i], __ATOMIC_ACQUIRE, __HIP_MEMORY_SCOPE_AGENT);
            float tt = (float)tsent[i];
            acc_l += tt * logf(p) + (1.f - tt) * logf(1.f - p);
        }
        acc_l = wave_reduce_sum(acc_l);
        if ((tid & 63) == 0) red2[tid >> 6] = acc_l;
        if (tid < NB) {
            float m = -3.4e38f;
            for (int s = 0; s < NS; ++s)
                m = fmaxf(m, __hip_atomic_load(&sent_ws[tid * NS + s], __ATOMIC_ACQUIRE,
                                               __HIP_MEMORY_SCOPE_AGENT));
            d_out[1 + NB * NS + tid] = m;
            float tt = (float)tdoc[tid];
            dred[tid] = tt * logf(m) + (1.f - tt) * logf(1.f - m);
        }
        __syncthreads();
        if (tid == 0) {
            float sal = -(red2[0] + red2[1] + red2[2] + red2[3]) / (float)(NB * NS);
            float dsum = 0.f;
            for (int i = 0; i < NB; ++i) dsum += dred[i];
            float dal = -dsum / (float)NB;
            d_out[0] = 0.5f * (sal + dal);
        }
    }
}

extern "C" void kernel_launch(void* const* d_in, const int* in_sizes, int n_in,
                              void* d_out, int out_size, void* d_ws, size_t ws_size,
                              hipStream_t stream) {
    const int* sentences = (const int*)d_in[0];
    const int* question = (const int*)d_in[1];
    const int* tsent = (const int*)d_in[2];
    const int* tdoc = (const int*)d_in[3];
    const float* sim_oh = (const float*)d_in[4];
    const float* embeds = (const float*)d_in[5];
    const float* conv_w = (const float*)d_in[6];
    const float* lin_w = (const float*)d_in[7];
    const float* lin_b = (const float*)d_in[8];
    float* out = (float*)d_out;

    char* wsc = (char*)d_ws;
    unsigned short* Wb     = (unsigned short*)(wsc);             // 491520 B
    unsigned short* qe     = (unsigned short*)(wsc + 491520);    // 368640 B
    float* q_norm          = (float*)(wsc + 860160);             // 2048 B
    unsigned short* q_conv = (unsigned short*)(wsc + 862208);    // 262144 B
    float* qc_norm         = (float*)(wsc + 1124352);            // 2048 B
    float* sent_ws         = (float*)(wsc + 1126400);            // 3072 B
    unsigned int* done_ctr = (unsigned int*)(wsc + 1129472);     // 4 B

    hipFuncSetAttribute(reinterpret_cast<const void*>(fused3_kernel),
                        hipFuncAttributeMaxDynamicSharedMemorySize, DYN_LDS);

    wb_kernel<<<960, 256, 0, stream>>>(conv_w, Wb, done_ctr);
    qe_kernel<<<NB * QROWS, 64, 0, stream>>>(question, embeds, qe, q_norm);
    qconv_mfma_kernel<<<NB, 256, 0, stream>>>(qe, Wb, q_conv, qc_norm);
    fused3_kernel<<<NB * NS, 256, DYN_LDS, stream>>>(
        sentences, question, sim_oh, embeds, Wb, qe, q_norm, q_conv, qc_norm,
        lin_w, lin_b, tsent, tdoc, done_ctr, sent_ws, out);
}